// Round 1
// baseline (1448.667 us; speedup 1.0000x reference)
//
#include <hip/hip_runtime.h>
#include <hip/hip_bf16.h>
#include <cstdint>

#define B_ 8
#define C_ 192
#define N_ 3136
#define K_ 9
#define OC_ 384

typedef unsigned int u32;

// ---------------- Kernel A: normalize + transpose + sq ----------------
// x: (B,C,N) -> pts (B,N,C) normalized, xT (B,N,C) raw, sq (B,N)
__global__ __launch_bounds__(256) void prep_k(const float* __restrict__ x,
                                              float* __restrict__ pts,
                                              float* __restrict__ xT,
                                              float* __restrict__ sq) {
    int g = blockIdx.x * 256 + threadIdx.x;      // node id, grid exact (98*256 = 25088)
    int b = g / N_, n = g % N_;
    const float* xb = x + (size_t)b * C_ * N_ + n;
    float ss = 0.f;
    for (int c = 0; c < C_; ++c) { float v = xb[(size_t)c * N_]; ss = fmaf(v, v, ss); }
    float den = fmaxf(sqrtf(ss), 1e-12f);
    float* prow = pts + (size_t)g * C_;
    float* xrow = xT + (size_t)g * C_;
    float s2 = 0.f;
    for (int c = 0; c < C_; ++c) {
        float v = xb[(size_t)c * N_];
        float p = v / den;                        // IEEE div, matches np elementwise divide
        prow[c] = p; xrow[c] = v;
        s2 = fmaf(p, p, s2);
    }
    sq[g] = s2;
}

// ---------------- Kernel B: fused distance GEMM + top-9 ----------------
// 64 queries x full 3136 candidates per block. 16x16 threads, 4q x 8m per thread.
// k staged in 3 chunks of 64. dist tile scanned by per-(query,quarter) threads
// keeping a running top-9; stable merge at the end.
__global__ __launch_bounds__(256) void knn_k(const float* __restrict__ pts,
                                             const float* __restrict__ sq,
                                             int* __restrict__ nn) {
    __shared__ float qc[64 * 72];     // [k][64 cols] granule-XOR swizzled
    __shared__ float un[64 * 137];    // union: mc [k][128 cols] swz (stride 136) / dist tile [64][137]
    __shared__ float sqs[128];
    const int tid = threadIdx.x;
    const int tx = tid & 15, ty = tid >> 4;
    const int qs = tid & 63, seg = tid >> 6;
    const int b = blockIdx.x / 49, qt = blockIdx.x % 49;
    const int q0 = qt * 64;
    const float* pb = pts + (size_t)b * N_ * C_;
    const float* sqb = sq + b * N_;

    float sqq[4];
    #pragma unroll
    for (int qi = 0; qi < 4; ++qi) sqq[qi] = sqb[q0 + 4 * ty + qi];

    float lv[9]; int li[9];
    #pragma unroll
    for (int r = 0; r < 9; ++r) { lv[r] = INFINITY; li[r] = 0x7fffffff; }
    float worst = INFINITY;

    for (int mt = 0; mt < 25; ++mt) {
        const int m0 = mt * 128;
        if (tid < 128) { int m = m0 + tid; sqs[tid] = (m < N_) ? sqb[m] : 0.f; }
        float acc[4][8];
        #pragma unroll
        for (int qi = 0; qi < 4; ++qi)
            #pragma unroll
            for (int j = 0; j < 8; ++j) acc[qi][j] = 0.f;

        for (int kc = 0; kc < 3; ++kc) {
            __syncthreads();   // protect previous users of qc/un before overwrite
            // ---- stage qc: 64 nodes x 64 k (coalesced global, swizzled LDS) ----
            #pragma unroll
            for (int i = 0; i < 4; ++i) {
                int e = tid + i * 256;
                int col = e >> 4, f = e & 15;
                float4 v = *(const float4*)&pb[(size_t)(q0 + col) * C_ + kc * 64 + 4 * f];
                int gq = col >> 2, r2 = col & 3;
                qc[(4*f+0)*72 + ((gq ^ ((4*f+0) & 15)) << 2) + r2] = v.x;
                qc[(4*f+1)*72 + ((gq ^ ((4*f+1) & 15)) << 2) + r2] = v.y;
                qc[(4*f+2)*72 + ((gq ^ ((4*f+2) & 15)) << 2) + r2] = v.z;
                qc[(4*f+3)*72 + ((gq ^ ((4*f+3) & 15)) << 2) + r2] = v.w;
            }
            // ---- stage mc: 128 nodes x 64 k ----
            #pragma unroll
            for (int i = 0; i < 8; ++i) {
                int e = tid + i * 256;
                int col = e >> 4, f = e & 15;
                int m = m0 + col;
                float4 v = make_float4(0.f, 0.f, 0.f, 0.f);
                if (m < N_) v = *(const float4*)&pb[(size_t)m * C_ + kc * 64 + 4 * f];
                int gm = col >> 2, r2 = col & 3;
                un[(4*f+0)*136 + ((gm ^ ((4*f+0) & 31)) << 2) + r2] = v.x;
                un[(4*f+1)*136 + ((gm ^ ((4*f+1) & 31)) << 2) + r2] = v.y;
                un[(4*f+2)*136 + ((gm ^ ((4*f+2) & 31)) << 2) + r2] = v.z;
                un[(4*f+3)*136 + ((gm ^ ((4*f+3) & 31)) << 2) + r2] = v.w;
            }
            __syncthreads();
            // ---- GEMM: 4q x 8m per thread over 64 k ----
            #pragma unroll 4
            for (int kk = 0; kk < 64; ++kk) {
                float4 qf  = *(const float4*)&qc[kk*72 + ((ty ^ (kk & 15)) << 2)];
                float4 mf0 = *(const float4*)&un[kk*136 + (((2*tx)   ^ (kk & 31)) << 2)];
                float4 mf1 = *(const float4*)&un[kk*136 + (((2*tx+1) ^ (kk & 31)) << 2)];
                float qv[4] = {qf.x, qf.y, qf.z, qf.w};
                float mv[8] = {mf0.x, mf0.y, mf0.z, mf0.w, mf1.x, mf1.y, mf1.z, mf1.w};
                #pragma unroll
                for (int qi = 0; qi < 4; ++qi)
                    #pragma unroll
                    for (int j = 0; j < 8; ++j)
                        acc[qi][j] = fmaf(qv[qi], mv[j], acc[qi][j]);
            }
        }
        __syncthreads();   // all mc reads done -> reuse un as dist tile
        // ---- epilogue: dist = (sq_n - 2*dot) + sq_m  (matches np rounding) ----
        #pragma unroll
        for (int qi = 0; qi < 4; ++qi) {
            #pragma unroll
            for (int j = 0; j < 8; ++j) {
                int ml = 8 * tx + j;
                float d = (sqq[qi] - 2.0f * acc[qi][j]) + sqs[ml];
                un[(4*ty+qi)*137 + ml] = d;
            }
        }
        __syncthreads();
        // ---- scan: thread (qs, seg) handles 32 candidates of query qs ----
        for (int j = 0; j < 32; ++j) {
            int ml = seg * 32 + j;
            int m = m0 + ml;
            float d = un[qs * 137 + ml];
            if (m < N_ && d < worst) {
                int sm = 0; float mx = lv[0];
                #pragma unroll
                for (int r = 1; r < 9; ++r) { if (lv[r] > mx) { mx = lv[r]; sm = r; } }
                #pragma unroll
                for (int r = 0; r < 9; ++r) if (r == sm) { lv[r] = d; li[r] = m; }
                float w2 = lv[0];
                #pragma unroll
                for (int r = 1; r < 9; ++r) w2 = fmaxf(w2, lv[r]);
                worst = w2;
            }
        }
    }
    __syncthreads();
    // ---- merge the 4 segment lists per query (stable: val asc, idx asc) ----
    float* Lv = qc; int* Li = (int*)un;
    #pragma unroll
    for (int r = 0; r < 9; ++r) { Lv[tid * 9 + r] = lv[r]; Li[tid * 9 + r] = li[r]; }
    __syncthreads();
    if (tid < 64) {
        int* onn = nn + ((size_t)b * N_ + q0 + tid) * K_;
        for (int r = 0; r < K_; ++r) {
            float best = INFINITY; int bidx = 0x7fffffff; int bp = 0;
            for (int s = 0; s < 4; ++s) {
                int base = (s * 64 + tid) * 9;
                for (int e = 0; e < 9; ++e) {
                    float v = Lv[base + e]; int id = Li[base + e];
                    if (v < best || (v == best && id < bidx)) { best = v; bidx = id; bp = base + e; }
                }
            }
            onn[r] = bidx;
            Lv[bp] = INFINITY;
        }
    }
}

// ---------------- Kernel C: channels 0..191 (x_i only -> k-independent) ----------------
__global__ __launch_bounds__(256) void convi_k(const float* __restrict__ x,
                                               const float* __restrict__ W,
                                               const float* __restrict__ bias,
                                               float* __restrict__ out) {
    __shared__ float Ws[48 * 96];
    const int orange = blockIdx.x & 3;
    const int nb = blockIdx.x >> 2;
    const int tid = threadIdx.x;
    const int g = nb * 256 + tid;
    const int b = g / N_, n = g % N_;
    const int o0 = orange * 48;
    const int cb = (o0 >= 96) ? 96 : 0;          // group 0 -> x_i[0..95], group 1 -> x_i[96..191]
    for (int i = 0; i < 18; ++i) {
        int e = tid + i * 256;
        Ws[e] = W[o0 * 96 + e];
    }
    __syncthreads();
    const float* xb = x + ((size_t)b * C_ + cb) * N_ + n;
    float xi[96];
    #pragma unroll
    for (int c = 0; c < 96; ++c) xi[c] = xb[(size_t)c * N_];
    float* ob = out + ((size_t)b * OC_ + o0) * N_ + n;
    for (int o = 0; o < 48; ++o) {
        float a = bias[o0 + o];
        #pragma unroll
        for (int c4 = 0; c4 < 24; ++c4) {
            float4 w4 = *(const float4*)&Ws[o * 96 + 4 * c4];
            a = fmaf(w4.x, xi[4*c4+0], a);
            a = fmaf(w4.y, xi[4*c4+1], a);
            a = fmaf(w4.z, xi[4*c4+2], a);
            a = fmaf(w4.w, xi[4*c4+3], a);
        }
        ob[(size_t)o * N_] = fmaxf(a, 0.f);
    }
}

// ---------------- Kernel D: channels 192..383 (x_j - x_i, max over k) ----------------
__device__ __forceinline__ float blo(u32 u) { return __uint_as_float(u << 16); }
__device__ __forceinline__ float bhi(u32 u) { return __uint_as_float(u & 0xffff0000u); }

__device__ __forceinline__ void rd9(float* d, const __hip_bfloat16* base, int c) {
    const u32* p = (const u32*)(base + c * 12);
    u32 u0 = p[0], u1 = p[1], u2 = p[2], u3 = p[3], u4 = p[4];
    d[0] = blo(u0); d[1] = bhi(u0); d[2] = blo(u1); d[3] = bhi(u1);
    d[4] = blo(u2); d[5] = bhi(u2); d[6] = blo(u3); d[7] = bhi(u3); d[8] = blo(u4);
}

__global__ __launch_bounds__(256) void convd_k(const float* __restrict__ xT,
                                               const int* __restrict__ nn,
                                               const float* __restrict__ W,
                                               const float* __restrict__ bias,
                                               float* __restrict__ out) {
    __shared__ __hip_bfloat16 Wb[192 * 104];     // rows = out ch 192+o, padded 104
    __shared__ __hip_bfloat16 dif[4][192 * 12];  // per-wave: [c][k 0..8 (+pad)]
    const int tid = threadIdx.x;
    const int w = tid >> 6, l = tid & 63;
    const int b = blockIdx.x / 196;
    const int n0 = (blockIdx.x % 196) * 16;

    for (int i = 0; i < 72; ++i) {
        int e = tid + i * 256;                   // 18432 = 192*96
        int row = e / 96, j = e % 96;
        Wb[row * 104 + j] = __float2bfloat16(W[(192 + row) * 96 + j]);
    }
    float bo[3];
    #pragma unroll
    for (int oi = 0; oi < 3; ++oi) bo[oi] = bias[192 + l + 64 * oi];
    __syncthreads();

    __hip_bfloat16* df = dif[w];
    const float* xTb = xT + (size_t)b * N_ * C_;
    float mx0[4], mx1[4], mx2[4];

    #pragma unroll
    for (int r = 0; r < 4; ++r) {
        const int n = n0 + 4 * w + r;            // wave w owns 4 consecutive nodes
        const float* xin = xTb + (size_t)n * C_;
        float xi0 = xin[l], xi1 = xin[l + 64], xi2 = xin[l + 128];
        const int* nb2 = nn + ((size_t)b * N_ + n) * K_;
        __syncthreads();                          // WAR vs previous round's reads
        #pragma unroll
        for (int k = 0; k < K_; ++k) {
            int idx = nb2[k];
            const float* xj = xTb + (size_t)idx * C_;
            df[(l)      * 12 + k] = __float2bfloat16(xj[l]       - xi0);
            df[(l + 64) * 12 + k] = __float2bfloat16(xj[l + 64]  - xi1);
            df[(l + 128)* 12 + k] = __float2bfloat16(xj[l + 128] - xi2);
        }
        __syncthreads();                          // writes visible
        float a0[9], a1[9], a2[9];
        #pragma unroll
        for (int k = 0; k < 9; ++k) { a0[k] = 0.f; a1[k] = 0.f; a2[k] = 0.f; }

        for (int jj = 0; jj < 12; ++jj) {
            float w0[8], w1[8], w2[8];
            {
                uint4 rw = *(const uint4*)(Wb + (size_t)(l)       * 104 + jj * 8);
                w0[0]=blo(rw.x); w0[1]=bhi(rw.x); w0[2]=blo(rw.y); w0[3]=bhi(rw.y);
                w0[4]=blo(rw.z); w0[5]=bhi(rw.z); w0[6]=blo(rw.w); w0[7]=bhi(rw.w);
            }
            {
                uint4 rw = *(const uint4*)(Wb + (size_t)(l + 64)  * 104 + jj * 8);
                w1[0]=blo(rw.x); w1[1]=bhi(rw.x); w1[2]=blo(rw.y); w1[3]=bhi(rw.y);
                w1[4]=blo(rw.z); w1[5]=bhi(rw.z); w1[6]=blo(rw.w); w1[7]=bhi(rw.w);
            }
            {
                uint4 rw = *(const uint4*)(Wb + (size_t)(l + 128) * 104 + jj * 8);
                w2[0]=blo(rw.x); w2[1]=bhi(rw.x); w2[2]=blo(rw.y); w2[3]=bhi(rw.y);
                w2[4]=blo(rw.z); w2[5]=bhi(rw.z); w2[6]=blo(rw.w); w2[7]=bhi(rw.w);
            }
            #pragma unroll
            for (int jr = 0; jr < 8; ++jr) {
                int j = jj * 8 + jr;
                int c0r = j;                              // o = l        (< 96): dif c = j
                int c2r = 96 + j;                         // o = l+128 (>=96): dif c = 96+j
                int c1r = (l >= 32) ? c2r : c0r;          // o = l+64: depends on lane
                float d0[9], d1[9], d2[9];
                rd9(d0, df, c0r); rd9(d1, df, c1r); rd9(d2, df, c2r);
                #pragma unroll
                for (int k = 0; k < 9; ++k) {
                    a0[k] = fmaf(w0[jr], d0[k], a0[k]);
                    a1[k] = fmaf(w1[jr], d1[k], a1[k]);
                    a2[k] = fmaf(w2[jr], d2[k], a2[k]);
                }
            }
        }
        // epilogue: relu(a + b) max over k  ==  max(max_k(a+b), 0)
        float m0 = a0[0] + bo[0], m1 = a1[0] + bo[1], m2 = a2[0] + bo[2];
        #pragma unroll
        for (int k = 1; k < 9; ++k) {
            m0 = fmaxf(m0, a0[k] + bo[0]);
            m1 = fmaxf(m1, a1[k] + bo[1]);
            m2 = fmaxf(m2, a2[k] + bo[2]);
        }
        mx0[r] = fmaxf(m0, 0.f); mx1[r] = fmaxf(m1, 0.f); mx2[r] = fmaxf(m2, 0.f);
    }
    float* ob = out + ((size_t)b * OC_ + 192) * N_ + n0 + 4 * w;
    *(float4*)&ob[(size_t)(l)       * N_] = make_float4(mx0[0], mx0[1], mx0[2], mx0[3]);
    *(float4*)&ob[(size_t)(l + 64)  * N_] = make_float4(mx1[0], mx1[1], mx1[2], mx1[3]);
    *(float4*)&ob[(size_t)(l + 128) * N_] = make_float4(mx2[0], mx2[1], mx2[2], mx2[3]);
}

extern "C" void kernel_launch(void* const* d_in, const int* in_sizes, int n_in,
                              void* d_out, int out_size, void* d_ws, size_t ws_size,
                              hipStream_t stream) {
    (void)in_sizes; (void)n_in; (void)out_size; (void)ws_size;
    const float* x    = (const float*)d_in[0];
    const float* W    = (const float*)d_in[1];
    const float* bias = (const float*)d_in[2];
    float* out = (float*)d_out;

    float* pts = (float*)d_ws;                       // 8*3136*192 f32
    float* xT  = pts + (size_t)B_ * N_ * C_;         // 8*3136*192 f32
    float* sq  = xT  + (size_t)B_ * N_ * C_;         // 8*3136 f32
    int*   nn  = (int*)(sq + (size_t)B_ * N_);       // 8*3136*9 i32   (~39.5 MB total)

    hipLaunchKernelGGL(prep_k,  dim3(98),   dim3(256), 0, stream, x, pts, xT, sq);
    hipLaunchKernelGGL(knn_k,   dim3(392),  dim3(256), 0, stream, pts, sq, nn);
    hipLaunchKernelGGL(convi_k, dim3(392),  dim3(256), 0, stream, x, W, bias, out);
    hipLaunchKernelGGL(convd_k, dim3(1568), dim3(256), 0, stream, xT, nn, W, bias, out);
}

// Round 2
// 1170.849 us; speedup vs baseline: 1.2373x; 1.2373x over previous
//
#include <hip/hip_runtime.h>
#include <hip/hip_bf16.h>
#include <cstdint>

#define B_ 8
#define C_ 192
#define N_ 3136
#define K_ 9
#define OC_ 384

typedef unsigned int u32;

// ---------------- Kernel A: normalize + transpose + sq ----------------
// x: (B,C,N) -> ptsT (B,C,N) normalized, xT (B,N,C) raw, sq (B,N)
__global__ __launch_bounds__(256) void prep_k(const float* __restrict__ x,
                                              float* __restrict__ ptsT,
                                              float* __restrict__ xT,
                                              float* __restrict__ sq) {
    int g = blockIdx.x * 256 + threadIdx.x;      // node id (98*256 = 25088 exact)
    int b = g / N_, n = g % N_;
    const float* xb = x + (size_t)b * C_ * N_ + n;
    float ss = 0.f;
    for (int c = 0; c < C_; ++c) { float v = xb[(size_t)c * N_]; ss = fmaf(v, v, ss); }
    float den = fmaxf(sqrtf(ss), 1e-12f);
    float* pb = ptsT + (size_t)b * C_ * N_ + n;
    float* xrow = xT + (size_t)g * C_;
    float s2 = 0.f;
    for (int c4 = 0; c4 < 48; ++c4) {
        float4 vv;
        float* pv = &vv.x;
        #pragma unroll
        for (int j = 0; j < 4; ++j) {
            int c = 4 * c4 + j;
            float v = xb[(size_t)c * N_];
            float p = v / den;                    // IEEE div, matches np divide
            pb[(size_t)c * N_] = p;               // coalesced scalar write (fixed c, lanes = n)
            pv[j] = v;
            s2 = fmaf(p, p, s2);
        }
        *(float4*)&xrow[4 * c4] = vv;             // own-row float4 write
    }
    sq[g] = s2;
}

// ---------------- Kernel B: fused distance GEMM + top-9 ----------------
// Block: 64 queries x all 3136 candidates. Q staged ONCE ([192k][64q], 48KB).
// M chunk [64k][128m] (32KB) double-duty as dist tile. Thread (tx,ty):
// 4 queries (4ty+qi), 8 m (4tx+j and 64+4tx+j) -> all LDS b128 accesses
// conflict-free (16B lane stride).
__global__ __launch_bounds__(256, 2) void knn_k(const float* __restrict__ ptsT,
                                                const float* __restrict__ sq,
                                                int* __restrict__ nn) {
    __shared__ float Q[192 * 64];                 // [k][q]
    __shared__ float Mt[64 * 128];                // [k][m] chunk / later dist [q][m]
    const int tid = threadIdx.x;
    const int tx = tid & 15, ty = (tid >> 4) & 15;
    const int qs = tid & 63, seg = tid >> 6;
    const int b = blockIdx.x / 49, qt = blockIdx.x % 49;
    const int q0 = qt * 64;
    const float* pb = ptsT + (size_t)b * C_ * N_;
    const float* sqb = sq + b * N_;

    // ---- stage Q once: coalesced global float4 -> b128 LDS, bank-balanced ----
    #pragma unroll
    for (int i = 0; i < 12; ++i) {
        int e = tid + i * 256;                    // 0..3071 granules
        int row = e >> 4, g4 = e & 15;
        *(float4*)&Q[row * 64 + 4 * g4] =
            *(const float4*)&pb[(size_t)row * N_ + q0 + 4 * g4];
    }
    float sqq[4];
    #pragma unroll
    for (int qi = 0; qi < 4; ++qi) sqq[qi] = sqb[q0 + 4 * ty + qi];

    float lv[9]; int li[9];
    #pragma unroll
    for (int r = 0; r < 9; ++r) { lv[r] = INFINITY; li[r] = 0x7fffffff; }
    float worst = INFINITY;

    for (int mt = 0; mt < 25; ++mt) {
        const int m0 = mt * 128;
        float acc[4][8];
        #pragma unroll
        for (int qi = 0; qi < 4; ++qi)
            #pragma unroll
            for (int j = 0; j < 8; ++j) acc[qi][j] = 0.f;

        for (int kc = 0; kc < 3; ++kc) {
            __syncthreads();                      // WAR: prior GEMM/scan reads of Mt done
            // ---- stage M chunk: [64 k][128 m] ----
            #pragma unroll
            for (int i = 0; i < 8; ++i) {
                int e = tid + i * 256;            // 0..2047 granules
                int row = e >> 5, g4 = e & 31;
                int m = m0 + 4 * g4;
                float4 v = make_float4(0.f, 0.f, 0.f, 0.f);
                if (m < N_)                       // N_%4==0 -> exact per-f4 guard
                    v = *(const float4*)&pb[(size_t)(64 * kc + row) * N_ + m];
                *(float4*)&Mt[row * 128 + 4 * g4] = v;
            }
            __syncthreads();
            // ---- GEMM: k ascending (matches reference-passing accumulation order) ----
            #pragma unroll 4
            for (int kk = 0; kk < 64; ++kk) {
                float4 qf  = *(const float4*)&Q[(64 * kc + kk) * 64 + 4 * ty];
                float4 mf0 = *(const float4*)&Mt[kk * 128 + 4 * tx];
                float4 mf1 = *(const float4*)&Mt[kk * 128 + 64 + 4 * tx];
                float qv[4] = {qf.x, qf.y, qf.z, qf.w};
                float mv[8] = {mf0.x, mf0.y, mf0.z, mf0.w, mf1.x, mf1.y, mf1.z, mf1.w};
                #pragma unroll
                for (int qi = 0; qi < 4; ++qi)
                    #pragma unroll
                    for (int j = 0; j < 8; ++j)
                        acc[qi][j] = fmaf(qv[qi], mv[j], acc[qi][j]);
            }
        }
        // ---- epilogue: dist = (sq_n - 2*dot) + sq_m ----
        float4 sqm0 = *(const float4*)&sqb[m0 + 4 * tx];       // mt=24 tail may read
        float4 sqm1 = *(const float4*)&sqb[m0 + 64 + 4 * tx];  // past sq (in-ws, masked below)
        float sm[8] = {sqm0.x, sqm0.y, sqm0.z, sqm0.w, sqm1.x, sqm1.y, sqm1.z, sqm1.w};
        __syncthreads();                          // GEMM reads done -> Mt becomes dist tile
        #pragma unroll
        for (int qi = 0; qi < 4; ++qi) {
            float d[8];
            #pragma unroll
            for (int j = 0; j < 8; ++j) d[j] = (sqq[qi] - 2.0f * acc[qi][j]) + sm[j];
            *(float4*)&Mt[(4 * ty + qi) * 128 + 4 * tx]      = make_float4(d[0], d[1], d[2], d[3]);
            *(float4*)&Mt[(4 * ty + qi) * 128 + 64 + 4 * tx] = make_float4(d[4], d[5], d[6], d[7]);
        }
        __syncthreads();
        // ---- scan: thread (qs,seg) scans 32 candidates, rotated start (bank-free) ----
        const int rot = qs & 31;
        for (int j = 0; j < 32; ++j) {
            int ml = seg * 32 + ((j + rot) & 31);
            int m = m0 + ml;
            float d = Mt[qs * 128 + ml];
            if (m < N_ && d < worst) {
                int sm2 = 0; float mx = lv[0];
                #pragma unroll
                for (int r = 1; r < 9; ++r) { if (lv[r] > mx) { mx = lv[r]; sm2 = r; } }
                #pragma unroll
                for (int r = 0; r < 9; ++r) if (r == sm2) { lv[r] = d; li[r] = m; }
                float w2 = lv[0];
                #pragma unroll
                for (int r = 1; r < 9; ++r) w2 = fmaxf(w2, lv[r]);
                worst = w2;
            }
        }
    }
    __syncthreads();
    // ---- merge 4 segment lists per query (stable: val asc, idx asc) ----
    float* Lv = Q;                                // alias: Q/Mt free now
    int*   Li = (int*)Mt;
    #pragma unroll
    for (int r = 0; r < 9; ++r) { Lv[tid * 9 + r] = lv[r]; Li[tid * 9 + r] = li[r]; }
    __syncthreads();
    if (tid < 64) {
        int* onn = nn + ((size_t)b * N_ + q0 + tid) * K_;
        for (int r = 0; r < K_; ++r) {
            float best = INFINITY; int bidx = 0x7fffffff; int bp = 0;
            for (int s = 0; s < 4; ++s) {
                int base = (s * 64 + tid) * 9;
                for (int e = 0; e < 9; ++e) {
                    float v = Lv[base + e]; int id = Li[base + e];
                    if (v < best || (v == best && id < bidx)) { best = v; bidx = id; bp = base + e; }
                }
            }
            onn[r] = bidx;
            Lv[bp] = INFINITY;
        }
    }
}

// ---------------- Kernel C: channels 0..191 (x_i only -> k-independent) ----------------
__global__ __launch_bounds__(256) void convi_k(const float* __restrict__ x,
                                               const float* __restrict__ W,
                                               const float* __restrict__ bias,
                                               float* __restrict__ out) {
    __shared__ float Ws[48 * 96];
    const int orange = blockIdx.x & 3;
    const int nb = blockIdx.x >> 2;
    const int tid = threadIdx.x;
    const int g = nb * 256 + tid;
    const int b = g / N_, n = g % N_;
    const int o0 = orange * 48;
    const int cb = (o0 >= 96) ? 96 : 0;
    for (int i = 0; i < 18; ++i) {
        int e = tid + i * 256;
        Ws[e] = W[o0 * 96 + e];
    }
    __syncthreads();
    const float* xb = x + ((size_t)b * C_ + cb) * N_ + n;
    float xi[96];
    #pragma unroll
    for (int c = 0; c < 96; ++c) xi[c] = xb[(size_t)c * N_];
    float* ob = out + ((size_t)b * OC_ + o0) * N_ + n;
    for (int o = 0; o < 48; ++o) {
        float a = bias[o0 + o];
        #pragma unroll
        for (int c4 = 0; c4 < 24; ++c4) {
            float4 w4 = *(const float4*)&Ws[o * 96 + 4 * c4];
            a = fmaf(w4.x, xi[4*c4+0], a);
            a = fmaf(w4.y, xi[4*c4+1], a);
            a = fmaf(w4.z, xi[4*c4+2], a);
            a = fmaf(w4.w, xi[4*c4+3], a);
        }
        ob[(size_t)o * N_] = fmaxf(a, 0.f);
    }
}

// ---------------- Kernel D: channels 192..383 (x_j - x_i, max over k) ----------------
__device__ __forceinline__ float blo(u32 u) { return __uint_as_float(u << 16); }
__device__ __forceinline__ float bhi(u32 u) { return __uint_as_float(u & 0xffff0000u); }

__device__ __forceinline__ void rd9(float* d, const __hip_bfloat16* base, int c) {
    const u32* p = (const u32*)(base + c * 12);
    u32 u0 = p[0], u1 = p[1], u2 = p[2], u3 = p[3], u4 = p[4];
    d[0] = blo(u0); d[1] = bhi(u0); d[2] = blo(u1); d[3] = bhi(u1);
    d[4] = blo(u2); d[5] = bhi(u2); d[6] = blo(u3); d[7] = bhi(u3); d[8] = blo(u4);
}

__global__ __launch_bounds__(256) void convd_k(const float* __restrict__ xT,
                                               const int* __restrict__ nn,
                                               const float* __restrict__ W,
                                               const float* __restrict__ bias,
                                               float* __restrict__ out) {
    __shared__ __hip_bfloat16 Wb[192 * 104];
    __shared__ __hip_bfloat16 dif[4][192 * 12];
    const int tid = threadIdx.x;
    const int w = tid >> 6, l = tid & 63;
    const int b = blockIdx.x / 196;
    const int n0 = (blockIdx.x % 196) * 16;

    for (int i = 0; i < 72; ++i) {
        int e = tid + i * 256;
        int row = e / 96, j = e % 96;
        Wb[row * 104 + j] = __float2bfloat16(W[(192 + row) * 96 + j]);
    }
    float bo[3];
    #pragma unroll
    for (int oi = 0; oi < 3; ++oi) bo[oi] = bias[192 + l + 64 * oi];
    __syncthreads();

    __hip_bfloat16* df = dif[w];
    const float* xTb = xT + (size_t)b * N_ * C_;
    float mx0[4], mx1[4], mx2[4];

    #pragma unroll
    for (int r = 0; r < 4; ++r) {
        const int n = n0 + 4 * w + r;
        const float* xin = xTb + (size_t)n * C_;
        float xi0 = xin[l], xi1 = xin[l + 64], xi2 = xin[l + 128];
        const int* nb2 = nn + ((size_t)b * N_ + n) * K_;
        __syncthreads();
        #pragma unroll
        for (int k = 0; k < K_; ++k) {
            int idx = nb2[k];
            const float* xj = xTb + (size_t)idx * C_;
            df[(l)      * 12 + k] = __float2bfloat16(xj[l]       - xi0);
            df[(l + 64) * 12 + k] = __float2bfloat16(xj[l + 64]  - xi1);
            df[(l + 128)* 12 + k] = __float2bfloat16(xj[l + 128] - xi2);
        }
        __syncthreads();
        float a0[9], a1[9], a2[9];
        #pragma unroll
        for (int k = 0; k < 9; ++k) { a0[k] = 0.f; a1[k] = 0.f; a2[k] = 0.f; }

        for (int jj = 0; jj < 12; ++jj) {
            float w0[8], w1[8], w2[8];
            {
                uint4 rw = *(const uint4*)(Wb + (size_t)(l)       * 104 + jj * 8);
                w0[0]=blo(rw.x); w0[1]=bhi(rw.x); w0[2]=blo(rw.y); w0[3]=bhi(rw.y);
                w0[4]=blo(rw.z); w0[5]=bhi(rw.z); w0[6]=blo(rw.w); w0[7]=bhi(rw.w);
            }
            {
                uint4 rw = *(const uint4*)(Wb + (size_t)(l + 64)  * 104 + jj * 8);
                w1[0]=blo(rw.x); w1[1]=bhi(rw.x); w1[2]=blo(rw.y); w1[3]=bhi(rw.y);
                w1[4]=blo(rw.z); w1[5]=bhi(rw.z); w1[6]=blo(rw.w); w1[7]=bhi(rw.w);
            }
            {
                uint4 rw = *(const uint4*)(Wb + (size_t)(l + 128) * 104 + jj * 8);
                w2[0]=blo(rw.x); w2[1]=bhi(rw.x); w2[2]=blo(rw.y); w2[3]=bhi(rw.y);
                w2[4]=blo(rw.z); w2[5]=bhi(rw.z); w2[6]=blo(rw.w); w2[7]=bhi(rw.w);
            }
            #pragma unroll
            for (int jr = 0; jr < 8; ++jr) {
                int j = jj * 8 + jr;
                int c0r = j;
                int c2r = 96 + j;
                int c1r = (l >= 32) ? c2r : c0r;
                float d0[9], d1[9], d2[9];
                rd9(d0, df, c0r); rd9(d1, df, c1r); rd9(d2, df, c2r);
                #pragma unroll
                for (int k = 0; k < 9; ++k) {
                    a0[k] = fmaf(w0[jr], d0[k], a0[k]);
                    a1[k] = fmaf(w1[jr], d1[k], a1[k]);
                    a2[k] = fmaf(w2[jr], d2[k], a2[k]);
                }
            }
        }
        float m0 = a0[0] + bo[0], m1 = a1[0] + bo[1], m2 = a2[0] + bo[2];
        #pragma unroll
        for (int k = 1; k < 9; ++k) {
            m0 = fmaxf(m0, a0[k] + bo[0]);
            m1 = fmaxf(m1, a1[k] + bo[1]);
            m2 = fmaxf(m2, a2[k] + bo[2]);
        }
        mx0[r] = fmaxf(m0, 0.f); mx1[r] = fmaxf(m1, 0.f); mx2[r] = fmaxf(m2, 0.f);
    }
    float* ob = out + ((size_t)b * OC_ + 192) * N_ + n0 + 4 * w;
    *(float4*)&ob[(size_t)(l)       * N_] = make_float4(mx0[0], mx0[1], mx0[2], mx0[3]);
    *(float4*)&ob[(size_t)(l + 64)  * N_] = make_float4(mx1[0], mx1[1], mx1[2], mx1[3]);
    *(float4*)&ob[(size_t)(l + 128) * N_] = make_float4(mx2[0], mx2[1], mx2[2], mx2[3]);
}

extern "C" void kernel_launch(void* const* d_in, const int* in_sizes, int n_in,
                              void* d_out, int out_size, void* d_ws, size_t ws_size,
                              hipStream_t stream) {
    (void)in_sizes; (void)n_in; (void)out_size; (void)ws_size;
    const float* x    = (const float*)d_in[0];
    const float* W    = (const float*)d_in[1];
    const float* bias = (const float*)d_in[2];
    float* out = (float*)d_out;

    float* ptsT = (float*)d_ws;                        // 8*192*3136 f32 (normalized, k-major)
    float* xT   = ptsT + (size_t)B_ * C_ * N_;         // 8*3136*192 f32 (raw, node-major)
    float* sq   = xT   + (size_t)B_ * N_ * C_;         // 8*3136 f32
    int*   nn   = (int*)(sq + (size_t)B_ * N_);        // 8*3136*9 i32

    hipLaunchKernelGGL(prep_k,  dim3(98),   dim3(256), 0, stream, x, ptsT, xT, sq);
    hipLaunchKernelGGL(knn_k,   dim3(392),  dim3(256), 0, stream, ptsT, sq, nn);
    hipLaunchKernelGGL(convi_k, dim3(392),  dim3(256), 0, stream, x, W, bias, out);
    hipLaunchKernelGGL(convd_k, dim3(1568), dim3(256), 0, stream, xT, nn, W, bias, out);
}